// Round 4
// baseline (590.112 us; speedup 1.0000x reference)
//
#include <hip/hip_runtime.h>
#include <math.h>

// DeltaCorrection, fully fused: one kernel, grid = (bh * 4 i-quarters) = 256
// blocks x 512 threads. Each block scans the 64 chunks of its stream with its
// 16x64 slice of the state S held in registers (f32x4 D-frag per wave 0-3).
// All matmuls are split-bf16 MFMA (3-term Ootomo: hi*hi + hi*lo + lo*hi).
// No workspace: q,k,v read once, out written once.

typedef __attribute__((ext_vector_type(8))) short bf16x8;
typedef __attribute__((ext_vector_type(4))) float f32x4;
typedef unsigned short ushort_t;

#define MFMA(a, b, c) __builtin_amdgcn_mfma_f32_16x16x32_bf16(a, b, c, 0, 0, 0)
#define GETC(v, u) ((u) == 0 ? (v).x : ((u) == 1 ? (v).y : ((u) == 2 ? (v).z : (v).w)))

__device__ __forceinline__ float sigf(float x) { return 1.0f / (1.0f + expf(-x)); }

// byte offset into a [R][64] bf16 LDS tile (R<=64), XOR-swizzled: b128 reads
// across lane-varying rows at a fixed 16B col-slot spread over 8 bank-slots.
__device__ __forceinline__ int swb(int row, int col) {
  return ((row << 7) + (col << 1)) ^ ((row & 7) << 4);
}

// split fp32 -> truncated bf16 hi + bf16(residual) lo
__device__ __forceinline__ void split1(float x, ushort_t& h, ushort_t& l) {
  unsigned xb = __float_as_uint(x);
  h = (ushort_t)(xb >> 16);
  float hf = __uint_as_float(xb & 0xFFFF0000u);
  float lf = x - hf;
  l = (ushort_t)(__float_as_uint(lf) >> 16);
}

// store float4 as hi/lo bf16, b64-packed, at (row, col..col+3); col % 4 == 0
__device__ __forceinline__ void st_split4(char* bh, char* bl, int row, int col, float4 v) {
  ushort_t h0, h1, h2, h3, l0, l1, l2, l3;
  split1(v.x, h0, l0); split1(v.y, h1, l1); split1(v.z, h2, l2); split1(v.w, h3, l3);
  uint2 hp, lp;
  hp.x = (unsigned)h0 | ((unsigned)h1 << 16); hp.y = (unsigned)h2 | ((unsigned)h3 << 16);
  lp.x = (unsigned)l0 | ((unsigned)l1 << 16); lp.y = (unsigned)l2 | ((unsigned)l3 << 16);
  int o = swb(row, col);
  *(uint2*)(bh + o) = hp;
  *(uint2*)(bl + o) = lp;
}

// A/B fragment for mfma_f32_16x16x32_bf16: lane holds row mrow+(lane&15),
// k = kk + (lane>>4)*8 .. +7 (contiguous in the stored tile)
__device__ __forceinline__ bf16x8 ldfrag(const char* base, int mrow, int kk, int lane) {
  int r = mrow + (lane & 15);
  int c = kk + ((lane >> 4) << 3);
  return *(const bf16x8*)(base + swb(r, c));
}

__global__ __launch_bounds__(512) void fused_delta(
    const float* __restrict__ qg, const float* __restrict__ kg,
    const float* __restrict__ vg,
    const float* __restrict__ w_decay, const float* __restrict__ b_decay,
    const float* __restrict__ w_write, const float* __restrict__ b_write,
    const float* __restrict__ out_scale, float* __restrict__ outg) {
  // LDS map (57.6 KB): QS 16K | KS 16K (aliased by SS after p1a) | KT 16K |
  //                    VT 4K | SL 4K | abuf 256B | dec 4B
  __shared__ uint4 smraw[3601];
  char* sm = (char*)smraw;
  char* QS_H = sm;             char* QS_L = sm + 8192;   // q   [t][d]
  char* KS_H = sm + 16384;     char* KS_L = sm + 24576;  // kf  [j][d]; ss [t][tau] after p1a
  char* KT_H = sm + 32768;     char* KT_L = sm + 40960;  // kf^T [d][t]
  char* VT_H = sm + 49152;     char* VT_L = sm + 51200;  // v^T [i_loc(16)][t]
  char* SL_H = sm + 53248;     char* SL_L = sm + 55296;  // S_{c-1} [i_loc(16)][j]
  float* abuf = (float*)(sm + 57344);
  float* decp = (float*)(sm + 57600);

  const int tid = threadIdx.x, lane = tid & 63, wv = tid >> 6;
  const int bh = blockIdx.x >> 2, qd = blockIdx.x & 3, ibase = qd * 16;
  const size_t sbase = (size_t)bh * 262144;  // 4096 * 64 elements per stream

  const float bwr = b_write[0], bdc = b_decay[0], osc = out_scale[0];

  // thread task coords
  const bool isK = (tid >= 256);
  const int tk = tid - 256, ktq = tk >> 4, kc4 = tk & 15;  // k-task (2nd half)
  const int qrow = tid >> 2, qc16 = (tid & 3) << 4;        // q-task (1st half)
  const int vtq = tid >> 2, vmq = tid & 3;                 // v-task (tid<64)
  float4 ww4 = make_float4(0.f, 0.f, 0.f, 0.f), wd4 = ww4;
  if (isK) {
    ww4 = *(const float4*)(w_write + kc4 * 4);
    wd4 = *(const float4*)(w_decay + kc4 * 4);
  }

  float4 qr0[4], qr1[4], vr0[4], vr1[4], kr0[4], kr1[4];

  auto LOADC = [&](float4 (&qr)[4], float4 (&vr)[4], float4 (&kr)[4], int c) {
    const size_t cb = sbase + (size_t)c * 4096;
    if (!isK) {
      const float* qp = qg + cb + qrow * 64 + qc16;
#pragma unroll
      for (int u = 0; u < 4; ++u) qr[u] = *(const float4*)(qp + 4 * u);
      if (tid < 64) {
#pragma unroll
        for (int e = 0; e < 4; ++e)
          vr[e] = *(const float4*)(vg + cb + (vtq * 4 + e) * 64 + ibase + vmq * 4);
      }
    } else {
#pragma unroll
      for (int e = 0; e < 4; ++e)
        kr[e] = *(const float4*)(kg + cb + (ktq * 4 + e) * 64 + kc4 * 4);
    }
  };

  f32x4 S = {0.f, 0.f, 0.f, 0.f};
  const f32x4 z = {0.f, 0.f, 0.f, 0.f};

  auto BODY = [&](float4 (&qr)[4], float4 (&vr)[4], float4 (&kr)[4], int c, int cnext) {
    // ---- stage chunk c from regs into LDS ----
    if (!isK) {
#pragma unroll
      for (int u = 0; u < 4; ++u) st_split4(QS_H, QS_L, qrow, qc16 + 4 * u, qr[u]);
      if (tid < 64) {
#pragma unroll
        for (int mm = 0; mm < 4; ++mm) {
          float4 tv = make_float4(GETC(vr[0], mm), GETC(vr[1], mm),
                                  GETC(vr[2], mm), GETC(vr[3], mm));
          st_split4(VT_H, VT_L, vmq * 4 + mm, vtq * 4, tv);  // v^T
        }
      }
    } else {
      float n2[4], dw[4], da[4];
#pragma unroll
      for (int e = 0; e < 4; ++e) {
        float4 k4 = kr[e];
        n2[e] = k4.x * k4.x + k4.y * k4.y + k4.z * k4.z + k4.w * k4.w;
        dw[e] = k4.x * ww4.x + k4.y * ww4.y + k4.z * ww4.z + k4.w * ww4.w;
        da[e] = k4.x * wd4.x + k4.y * wd4.y + k4.z * wd4.z + k4.w * wd4.w;
      }
#pragma unroll
      for (int m = 1; m < 16; m <<= 1) {
#pragma unroll
        for (int e = 0; e < 4; ++e) {
          n2[e] += __shfl_xor(n2[e], m, 64);
          dw[e] += __shfl_xor(dw[e], m, 64);
          da[e] += __shfl_xor(da[e], m, 64);
        }
      }
      float4 kf[4];
#pragma unroll
      for (int e = 0; e < 4; ++e) {
        float beta  = sigf(dw[e] + bwr);
        float alpha = sigf(da[e] + bdc);
        float fold  = beta / fmaxf(sqrtf(n2[e]), 1e-12f);
        if (kc4 == 0) abuf[ktq * 4 + e] = alpha;
        kf[e] = make_float4(kr[e].x * fold, kr[e].y * fold, kr[e].z * fold, kr[e].w * fold);
        st_split4(KS_H, KS_L, ktq * 4 + e, kc4 * 4, kf[e]);  // kf natural
      }
#pragma unroll
      for (int m = 0; m < 4; ++m) {  // register 4x4 transpose -> kf^T, b64-packed
        float4 tv = make_float4(GETC(kf[0], m), GETC(kf[1], m),
                                GETC(kf[2], m), GETC(kf[3], m));
        st_split4(KT_H, KT_L, kc4 * 4 + m, ktq * 4, tv);
      }
    }
    // prefetch chunk c+2 into the regs just consumed (in flight across phases)
    LOADC(qr, vr, kr, cnext);
    __syncthreads();

    // ---- p1a: scores D[j][t] = kf . q  (2 tiles/wave, all 8 waves) ----
    f32x4 sc[2] = {z, z};
    __builtin_amdgcn_s_setprio(1);
#pragma unroll
    for (int s = 0; s < 2; ++s) {
      int tt = wv * 2 + s, jb = tt >> 2, tb = tt & 3;
#pragma unroll
      for (int kk = 0; kk < 64; kk += 32) {
        bf16x8 ah = ldfrag(KS_H, jb * 16, kk, lane), al = ldfrag(KS_L, jb * 16, kk, lane);
        bf16x8 bh_ = ldfrag(QS_H, tb * 16, kk, lane), bl_ = ldfrag(QS_L, tb * 16, kk, lane);
        sc[s] = MFMA(ah, bh_, sc[s]);
        sc[s] = MFMA(ah, bl_, sc[s]);
        sc[s] = MFMA(al, bh_, sc[s]);
      }
    }
    __builtin_amdgcn_s_setprio(0);
    if (wv == 4) {  // chunk decay = mean(alpha)^64
      float a = abuf[lane];
#pragma unroll
      for (int off = 32; off; off >>= 1) a += __shfl_down(a, off, 64);
      if (lane == 0) {
        float m_ = a * (1.0f / 64.0f);
        float p = m_ * m_; p = p * p; p = p * p; p = p * p; p = p * p; p = p * p;
        *decp = p;
      }
    }
    __syncthreads();  // KS reads done -> ss may overwrite KS

    // ---- p1b: masked ss -> SS (=KS region); kv MFMA + S_{c-1} -> SL ----
#pragma unroll
    for (int s = 0; s < 2; ++s) {
      int tt = wv * 2 + s, jb = tt >> 2, tb = tt & 3;
      int tcol = tb * 16 + (lane & 15), j0 = jb * 16 + ((lane >> 4) << 2);
      float x0 = (j0 + 0 <= tcol) ? sc[s][0] : 0.f;
      float x1 = (j0 + 1 <= tcol) ? sc[s][1] : 0.f;
      float x2 = (j0 + 2 <= tcol) ? sc[s][2] : 0.f;
      float x3 = (j0 + 3 <= tcol) ? sc[s][3] : 0.f;
      st_split4(KS_H, KS_L, tcol, j0, make_float4(x0, x1, x2, x3));  // ss[t][tau]
    }
    f32x4 kvacc = z;
    if (wv < 4) {
      int j = wv * 16 + (lane & 15), i0 = (lane >> 4) << 2;
#pragma unroll
      for (int r = 0; r < 4; ++r) {  // S_{c-1} -> SL (read by inter in p2)
        ushort_t h, l;
        split1(S[r], h, l);
        int o = swb(i0 + r, j);
        *(ushort_t*)(SL_H + o) = h;
        *(ushort_t*)(SL_L + o) = l;
      }
      __builtin_amdgcn_s_setprio(1);
#pragma unroll
      for (int kk = 0; kk < 64; kk += 32) {  // kv[i][j] = v^T . kf^T
        bf16x8 ah = ldfrag(VT_H, 0, kk, lane), al = ldfrag(VT_L, 0, kk, lane);
        bf16x8 bh_ = ldfrag(KT_H, wv * 16, kk, lane), bl_ = ldfrag(KT_L, wv * 16, kk, lane);
        kvacc = MFMA(ah, bh_, kvacc);
        kvacc = MFMA(ah, bl_, kvacc);
        kvacc = MFMA(al, bh_, kvacc);
      }
      __builtin_amdgcn_s_setprio(0);
    }
    __syncthreads();

    // ---- p2: out[i][t] = S . q + v^T . ss (waves 4-7); S update (waves 0-3) ----
    if (wv >= 4) {
      int tb = wv - 4;
      f32x4 acc = z;
      __builtin_amdgcn_s_setprio(1);
#pragma unroll
      for (int kk = 0; kk < 64; kk += 32) {
        bf16x8 ah = ldfrag(SL_H, 0, kk, lane), al = ldfrag(SL_L, 0, kk, lane);
        bf16x8 bh_ = ldfrag(QS_H, tb * 16, kk, lane), bl_ = ldfrag(QS_L, tb * 16, kk, lane);
        acc = MFMA(ah, bh_, acc);   // inter^T
        acc = MFMA(ah, bl_, acc);
        acc = MFMA(al, bh_, acc);
        bf16x8 ch = ldfrag(VT_H, 0, kk, lane), cl = ldfrag(VT_L, 0, kk, lane);
        bf16x8 dh = ldfrag(KS_H, tb * 16, kk, lane), dl = ldfrag(KS_L, tb * 16, kk, lane);
        acc = MFMA(ch, dh, acc);    // intra^T (ss lives in KS region)
        acc = MFMA(ch, dl, acc);
        acc = MFMA(cl, dh, acc);
      }
      __builtin_amdgcn_s_setprio(0);
      int t = tb * 16 + (lane & 15), i0 = (lane >> 4) << 2;
      float4 o = make_float4(acc[0] * osc, acc[1] * osc, acc[2] * osc, acc[3] * osc);
      *(float4*)(outg + sbase + (size_t)c * 4096 + t * 64 + ibase + i0) = o;
    } else {
      float dcy = *decp;
      S[0] = fmaf(dcy, S[0], kvacc[0]);
      S[1] = fmaf(dcy, S[1], kvacc[1]);
      S[2] = fmaf(dcy, S[2], kvacc[2]);
      S[3] = fmaf(dcy, S[3], kvacc[3]);
    }
    __syncthreads();  // protect LDS before next chunk's staging
  };

  LOADC(qr0, vr0, kr0, 0);
  LOADC(qr1, vr1, kr1, 1);
  for (int c = 0; c < 64; c += 2) {
    BODY(qr0, vr0, kr0, c,     (c + 2 < 64) ? c + 2 : 63);
    BODY(qr1, vr1, kr1, c + 1, (c + 3 < 64) ? c + 3 : 63);
  }
}

// ---------------------------------------------------------------------------
extern "C" void kernel_launch(void* const* d_in, const int* in_sizes, int n_in,
                              void* d_out, int out_size, void* d_ws, size_t ws_size,
                              hipStream_t stream) {
  const float* q         = (const float*)d_in[0];
  const float* k         = (const float*)d_in[1];
  const float* v         = (const float*)d_in[2];
  const float* w_decay   = (const float*)d_in[3];
  const float* b_decay   = (const float*)d_in[4];
  const float* w_write   = (const float*)d_in[5];
  const float* b_write   = (const float*)d_in[6];
  const float* out_scale = (const float*)d_in[7];
  float* out = (float*)d_out;

  fused_delta<<<dim3(256), dim3(512), 0, stream>>>(
      q, k, v, w_decay, b_decay, w_write, b_write, out_scale, out);
}

// Round 5
// 288.661 us; speedup vs baseline: 2.0443x; 2.0443x over previous
//
#include <hip/hip_runtime.h>
#include <math.h>

// DeltaCorrection via split-bf16 MFMA (3-term Ootomo: hi*hi + hi*lo + lo*hi).
// K1: per-chunk kv (d x d) + chunk decay      (4096 blocks, MFMA, 4 blocks/CU)
// K2: elementwise in-place scan over chunks   (256 blocks, 8-deep pipelined)
// K3: scoresT -> masked ss -> out = q*S^T + ss*v  (4096 blocks, MFMA, 3 blocks/CU,
//     S-fragments register-loaded from global, direct C-stores, 3 barriers)

#define NCH 64
#define NBH 64

typedef __attribute__((ext_vector_type(8))) short bf16x8;
typedef __attribute__((ext_vector_type(4))) float f32x4;
typedef unsigned short ushort_t;

#define MFMA(a, b, c) __builtin_amdgcn_mfma_f32_16x16x32_bf16(a, b, c, 0, 0, 0)
#define GETC(v, u) ((u) == 0 ? (v).x : ((u) == 1 ? (v).y : ((u) == 2 ? (v).z : (v).w)))

__device__ __forceinline__ float sigf(float x) { return 1.0f / (1.0f + expf(-x)); }

// byte offset into a [64][64] bf16 LDS array, XOR-swizzled so that b128 reads
// across lane-varying rows at fixed 16B col-slot spread over 8 bank-slots.
__device__ __forceinline__ int swb(int row, int col) {
  return ((row << 7) + (col << 1)) ^ ((row & 7) << 4);
}

// split fp32 -> truncated bf16 hi + bf16(residual) lo.  |x - hi - lo| <= 2^-16 |x|
__device__ __forceinline__ void split1(float x, ushort_t& h, ushort_t& l) {
  unsigned xb = __float_as_uint(x);
  h = (ushort_t)(xb >> 16);
  float hf = __uint_as_float(xb & 0xFFFF0000u);
  float lf = x - hf;
  l = (ushort_t)(__float_as_uint(lf) >> 16);
}

// store float4 as hi/lo bf16, b64-packed, at (row, col..col+3); col % 4 == 0
__device__ __forceinline__ void st_split4(char* bh, char* bl, int row, int col, float4 v) {
  ushort_t h0, h1, h2, h3, l0, l1, l2, l3;
  split1(v.x, h0, l0); split1(v.y, h1, l1); split1(v.z, h2, l2); split1(v.w, h3, l3);
  uint2 hp, lp;
  hp.x = (unsigned)h0 | ((unsigned)h1 << 16); hp.y = (unsigned)h2 | ((unsigned)h3 << 16);
  lp.x = (unsigned)l0 | ((unsigned)l1 << 16); lp.y = (unsigned)l2 | ((unsigned)l3 << 16);
  int o = swb(row, col);
  *(uint2*)(bh + o) = hp;
  *(uint2*)(bl + o) = lp;
}

// A/B fragment for mfma_f32_16x16x32_bf16: lane holds row mrow+(lane&15),
// k = kk + (lane>>4)*8 .. +7 (contiguous in the stored tile)
__device__ __forceinline__ bf16x8 ldfrag(const char* base, int mrow, int kk, int lane) {
  int r = mrow + (lane & 15);
  int c = kk + ((lane >> 4) << 3);
  return *(const bf16x8*)(base + swb(r, c));
}

// split 8 fp32 (two float4, k-contiguous) into hi/lo bf16x8 fragments
__device__ __forceinline__ void split8(float4 a, float4 b, bf16x8& h, bf16x8& l) {
  float x[8] = {a.x, a.y, a.z, a.w, b.x, b.y, b.z, b.w};
  bf16x8 hh, ll;
#pragma unroll
  for (int i = 0; i < 8; ++i) {
    ushort_t hi, lo;
    split1(x[i], hi, lo);
    hh[i] = (short)hi; ll[i] = (short)lo;
  }
  h = hh; l = ll;
}

// ---------------------------------------------------------------------------
// K1: kv[i][j] = sum_t v[t][i] * (beta_t * khat[t][j]);  decay[bh][c]
// ---------------------------------------------------------------------------
__global__ __launch_bounds__(256, 4) void k1_kvdecay(
    const float* __restrict__ kg, const float* __restrict__ vg,
    const float* __restrict__ w_decay, const float* __restrict__ b_decay,
    const float* __restrict__ w_write, const float* __restrict__ b_write,
    float* __restrict__ ws_kv, float* __restrict__ ws_decay) {
  __shared__ uint4 smraw[2064];  // 33 KB -> 4 blocks/CU
  char* sm = (char*)smraw;
  char* KT_H = sm;             // kf^T [j][t] hi   (j = feature, t = time)
  char* KT_L = sm + 8192;
  char* VT_H = sm + 16384;     // v^T  [i][t]
  char* VT_L = sm + 24576;
  float* abuf = (float*)(sm + 32768);

  const int tid = threadIdx.x;
  const int lane = tid & 63, wv = tid >> 6;
  const int bh = blockIdx.x >> 6, cid = blockIdx.x & 63;
  const size_t gbase = (size_t)(bh * 4096 + cid * 64) * 64;

  // ---- load + gates + scatter-transpose staging ----
  {
    const int t = tid >> 2, g = tid & 3;
    const float* kp = kg + gbase + t * 64 + g * 16;
    const float* vp = vg + gbase + t * 64 + g * 16;
    float4 kr[4], vr[4];
#pragma unroll
    for (int u = 0; u < 4; ++u) { kr[u] = *(const float4*)(kp + 4 * u); vr[u] = *(const float4*)(vp + 4 * u); }
    float n2 = 0.f, dw = 0.f, da = 0.f;
#pragma unroll
    for (int u = 0; u < 4; ++u) {
      const float* wwp = w_write + g * 16 + 4 * u;
      const float* wdp = w_decay + g * 16 + 4 * u;
      float4 k4 = kr[u];
      n2 = fmaf(k4.x, k4.x, fmaf(k4.y, k4.y, fmaf(k4.z, k4.z, fmaf(k4.w, k4.w, n2))));
      dw = fmaf(k4.x, wwp[0], fmaf(k4.y, wwp[1], fmaf(k4.z, wwp[2], fmaf(k4.w, wwp[3], dw))));
      da = fmaf(k4.x, wdp[0], fmaf(k4.y, wdp[1], fmaf(k4.z, wdp[2], fmaf(k4.w, wdp[3], da))));
    }
    n2 += __shfl_xor(n2, 1, 64); n2 += __shfl_xor(n2, 2, 64);
    dw += __shfl_xor(dw, 1, 64); dw += __shfl_xor(dw, 2, 64);
    da += __shfl_xor(da, 1, 64); da += __shfl_xor(da, 2, 64);
    float beta  = sigf(dw + b_write[0]);
    float alpha = sigf(da + b_decay[0]);
    float fold  = beta / fmaxf(sqrtf(n2), 1e-12f);
    if (g == 0) abuf[t] = alpha;
#pragma unroll
    for (int u = 0; u < 4; ++u) {
      float kf[4] = {kr[u].x * fold, kr[u].y * fold, kr[u].z * fold, kr[u].w * fold};
      float vf[4] = {vr[u].x, vr[u].y, vr[u].z, vr[u].w};
#pragma unroll
      for (int e = 0; e < 4; ++e) {
        int row = g * 16 + 4 * u + e;
        ushort_t h, l;
        int o = swb(row, t);
        split1(kf[e], h, l);
        *(ushort_t*)(KT_H + o) = h; *(ushort_t*)(KT_L + o) = l;
        split1(vf[e], h, l);
        *(ushort_t*)(VT_H + o) = h; *(ushort_t*)(VT_L + o) = l;
      }
    }
  }
  __syncthreads();

  // ---- chunk decay (wave 0) ----
  if (tid < 64) {
    float a = abuf[tid];
    for (int off = 32; off; off >>= 1) a += __shfl_down(a, off, 64);
    if (tid == 0) {
      float m = a * (1.0f / 64.0f);
      float p = m * m; p = p * p; p = p * p; p = p * p; p = p * p; p = p * p;  // m^64
      ws_decay[bh * NCH + cid] = p;
    }
  }

  // ---- kv = mfma(A=v^T [i][t], B-src=kf^T [j][t]) -> D[i][j]; direct stores ----
  f32x4 z = {0.f, 0.f, 0.f, 0.f};
  f32x4 acc[4] = {z, z, z, z};
#pragma unroll
  for (int kk = 0; kk < 64; kk += 32) {
    bf16x8 ah = ldfrag(VT_H, wv * 16, kk, lane);
    bf16x8 al = ldfrag(VT_L, wv * 16, kk, lane);
#pragma unroll
    for (int jb = 0; jb < 4; ++jb) {
      bf16x8 bh_ = ldfrag(KT_H, jb * 16, kk, lane);
      bf16x8 bl_ = ldfrag(KT_L, jb * 16, kk, lane);
      acc[jb] = MFMA(ah, bh_, acc[jb]);
      acc[jb] = MFMA(ah, bl_, acc[jb]);
      acc[jb] = MFMA(al, bh_, acc[jb]);
    }
  }
  float* kvout = ws_kv + (size_t)(bh * NCH + cid) * 4096;
  {
    int i0 = wv * 16 + ((lane >> 4) << 2);
#pragma unroll
    for (int jb = 0; jb < 4; ++jb) {
      int j = jb * 16 + (lane & 15);
#pragma unroll
      for (int r = 0; r < 4; ++r) kvout[(i0 + r) * 64 + j] = acc[jb][r];
    }
  }
}

// ---------------------------------------------------------------------------
// K2: in-place scan; after: slot c holds S_{c-1} (slot 0 = zeros).
// ---------------------------------------------------------------------------
__global__ __launch_bounds__(256) void k2_scan(float* __restrict__ ws_kv,
                                               const float* __restrict__ ws_decay) {
  const int bh = blockIdx.x >> 2;
  const int pos = (blockIdx.x & 3) * 256 + threadIdx.x;
  float4* base = (float4*)ws_kv + (size_t)bh * 65536 + pos;
  const float* dec = ws_decay + bh * NCH;
  float4 S = make_float4(0.f, 0.f, 0.f, 0.f);
#pragma unroll
  for (int gq = 0; gq < 8; ++gq) {
    float4 buf[8];
#pragma unroll
    for (int j = 0; j < 8; ++j) buf[j] = base[(size_t)(gq * 8 + j) * 1024];
#pragma unroll
    for (int j = 0; j < 8; ++j) {
      int c = gq * 8 + j;
      float dcy = dec[c];
      base[(size_t)c * 1024] = S;
      S.x = fmaf(dcy, S.x, buf[j].x);
      S.y = fmaf(dcy, S.y, buf[j].y);
      S.z = fmaf(dcy, S.z, buf[j].z);
      S.w = fmaf(dcy, S.w, buf[j].w);
    }
  }
}

// ---------------------------------------------------------------------------
// K3: ssT[j][t] = kf[j].q[t] (masked j<=t) ; out[t][i] = q.S^T + ss.v , *scale
// LDS 48KB: QS, KS (PS aliases KS after phase A), VT. S-frags from global.
// ---------------------------------------------------------------------------
__global__ __launch_bounds__(256, 3) void k3_out(
    const float* __restrict__ qg, const float* __restrict__ kg,
    const float* __restrict__ vg,
    const float* __restrict__ w_write, const float* __restrict__ b_write,
    const float* __restrict__ out_scale,
    const float* __restrict__ ws_kv, float* __restrict__ outg) {
  __shared__ uint4 smraw[3072];  // 48 KB -> 3 blocks/CU
  char* sm = (char*)smraw;
  char* QS_H = sm;             char* QS_L = sm + 8192;   // q   [t][d]
  char* KS_H = sm + 16384;     char* KS_L = sm + 24576;  // kf  [j][d]; ss [t][tau] after p1a
  char* VT_H = sm + 32768;     char* VT_L = sm + 40960;  // v^T [i][t]
  char* PS_H = KS_H;           char* PS_L = KS_L;

  const int tid = threadIdx.x;
  const int lane = tid & 63, wv = tid >> 6;
  const int bh = blockIdx.x >> 6, cid = blockIdx.x & 63;
  const size_t gbase = (size_t)(bh * 4096 + cid * 64) * 64;
  const float* Sg = ws_kv + (size_t)(bh * NCH + cid) * 4096;

  // ---- stage q ----
#pragma unroll
  for (int rr = 0; rr < 4; ++rr) {
    int f = tid + 256 * rr;
    int row = f >> 4, c4 = (f & 15) * 4;
    float4 qq = *(const float4*)(qg + gbase + row * 64 + c4);
    st_split4(QS_H, QS_L, row, c4, qq);
  }
  // ---- stage v^T via 4x4 register transpose (b64 LDS writes, ~2-way banks) ----
  {
    const int rq = tid & 15, cq = tid >> 4;  // rows 4rq..+3, cols 4cq..+3
    float4 vv[4];
#pragma unroll
    for (int e = 0; e < 4; ++e)
      vv[e] = *(const float4*)(vg + gbase + (4 * rq + e) * 64 + 4 * cq);
#pragma unroll
    for (int m = 0; m < 4; ++m) {
      float4 tv = make_float4(GETC(vv[0], m), GETC(vv[1], m), GETC(vv[2], m), GETC(vv[3], m));
      st_split4(VT_H, VT_L, 4 * cq + m, 4 * rq, tv);
    }
  }
  // ---- stage kf (fold beta/norm in registers) ----
  {
    const int t = tid >> 2, g = tid & 3;
    const float* kp = kg + gbase + t * 64 + g * 16;
    float4 kr[4];
#pragma unroll
    for (int u = 0; u < 4; ++u) kr[u] = *(const float4*)(kp + 4 * u);
    float n2 = 0.f, dw = 0.f;
#pragma unroll
    for (int u = 0; u < 4; ++u) {
      const float* wwp = w_write + g * 16 + 4 * u;
      float4 k4 = kr[u];
      n2 = fmaf(k4.x, k4.x, fmaf(k4.y, k4.y, fmaf(k4.z, k4.z, fmaf(k4.w, k4.w, n2))));
      dw = fmaf(k4.x, wwp[0], fmaf(k4.y, wwp[1], fmaf(k4.z, wwp[2], fmaf(k4.w, wwp[3], dw))));
    }
    n2 += __shfl_xor(n2, 1, 64); n2 += __shfl_xor(n2, 2, 64);
    dw += __shfl_xor(dw, 1, 64); dw += __shfl_xor(dw, 2, 64);
    float beta = sigf(dw + b_write[0]);
    float fold = beta / fmaxf(sqrtf(n2), 1e-12f);
#pragma unroll
    for (int u = 0; u < 4; ++u) {
      float4 kf4 = make_float4(kr[u].x * fold, kr[u].y * fold, kr[u].z * fold, kr[u].w * fold);
      st_split4(KS_H, KS_L, t, g * 16 + 4 * u, kf4);
    }
  }
  __syncthreads();

  // ---- phase A: ssT[j][t] = sum_d kf[j][d] q[t][d] ----
  f32x4 z = {0.f, 0.f, 0.f, 0.f};
  f32x4 accs[4] = {z, z, z, z};
#pragma unroll
  for (int kk = 0; kk < 64; kk += 32) {
    bf16x8 ah = ldfrag(KS_H, wv * 16, kk, lane);
    bf16x8 al = ldfrag(KS_L, wv * 16, kk, lane);
#pragma unroll
    for (int nb = 0; nb < 4; ++nb) {
      bf16x8 bh_ = ldfrag(QS_H, nb * 16, kk, lane);
      bf16x8 bl_ = ldfrag(QS_L, nb * 16, kk, lane);
      accs[nb] = MFMA(ah, bh_, accs[nb]);
      accs[nb] = MFMA(ah, bl_, accs[nb]);
      accs[nb] = MFMA(al, bh_, accs[nb]);
    }
  }
  __syncthreads();  // all phase-A reads of KS/QS done -> PS may overwrite KS

  // ---- issue S B-fragment loads (global, consumed in phase B) ----
  float4 sraw[16];
  {
    const int l15 = lane & 15, g8 = (lane >> 4) << 3;
#pragma unroll
    for (int ib = 0; ib < 4; ++ib) {
#pragma unroll
      for (int k2 = 0; k2 < 2; ++k2) {
        const float* p = Sg + (ib * 16 + l15) * 64 + k2 * 32 + g8;
        sraw[ib * 4 + k2 * 2 + 0] = *(const float4*)(p);
        sraw[ib * 4 + k2 * 2 + 1] = *(const float4*)(p + 4);
      }
    }
  }

  // ---- write masked scores to PS [t][j] ----
#pragma unroll
  for (int nb = 0; nb < 4; ++nb) {
    int tcol = nb * 16 + (lane & 15);
    int j0 = wv * 16 + ((lane >> 4) << 2);
    float x0 = (j0 + 0 <= tcol) ? accs[nb][0] : 0.f;
    float x1 = (j0 + 1 <= tcol) ? accs[nb][1] : 0.f;
    float x2 = (j0 + 2 <= tcol) ? accs[nb][2] : 0.f;
    float x3 = (j0 + 3 <= tcol) ? accs[nb][3] : 0.f;
    st_split4(PS_H, PS_L, tcol, j0, make_float4(x0, x1, x2, x3));
  }
  __syncthreads();

  // ---- phase B: out[t][i] = sum_j q[t][j] S[i][j] + sum_j ss[t][j] vT[i][j] ----
  f32x4 acco[4] = {z, z, z, z};
#pragma unroll
  for (int k2 = 0; k2 < 2; ++k2) {
    const int kk = k2 * 32;
    bf16x8 qh = ldfrag(QS_H, wv * 16, kk, lane);
    bf16x8 ql = ldfrag(QS_L, wv * 16, kk, lane);
    bf16x8 ph = ldfrag(PS_H, wv * 16, kk, lane);
    bf16x8 pl = ldfrag(PS_L, wv * 16, kk, lane);
#pragma unroll
    for (int ib = 0; ib < 4; ++ib) {
      bf16x8 sh, sl;
      split8(sraw[ib * 4 + k2 * 2 + 0], sraw[ib * 4 + k2 * 2 + 1], sh, sl);
      acco[ib] = MFMA(qh, sh, acco[ib]);   // inter
      acco[ib] = MFMA(qh, sl, acco[ib]);
      acco[ib] = MFMA(ql, sh, acco[ib]);
      bf16x8 vh = ldfrag(VT_H, ib * 16, kk, lane);
      bf16x8 vl = ldfrag(VT_L, ib * 16, kk, lane);
      acco[ib] = MFMA(ph, vh, acco[ib]);   // intra
      acco[ib] = MFMA(ph, vl, acco[ib]);
      acco[ib] = MFMA(pl, vh, acco[ib]);
    }
  }

  // ---- direct C-stores (64B segments per 16-lane group) ----
  const float osc = out_scale[0];
  {
    int t0 = wv * 16 + ((lane >> 4) << 2);
    int l15 = lane & 15;
#pragma unroll
    for (int ib = 0; ib < 4; ++ib) {
#pragma unroll
      for (int r = 0; r < 4; ++r)
        outg[gbase + (t0 + r) * 64 + ib * 16 + l15] = acco[ib][r] * osc;
    }
  }
}

// ---------------------------------------------------------------------------
extern "C" void kernel_launch(void* const* d_in, const int* in_sizes, int n_in,
                              void* d_out, int out_size, void* d_ws, size_t ws_size,
                              hipStream_t stream) {
  const float* q         = (const float*)d_in[0];
  const float* k         = (const float*)d_in[1];
  const float* v         = (const float*)d_in[2];
  const float* w_decay   = (const float*)d_in[3];
  const float* b_decay   = (const float*)d_in[4];
  const float* w_write   = (const float*)d_in[5];
  const float* b_write   = (const float*)d_in[6];
  const float* out_scale = (const float*)d_in[7];
  float* out = (float*)d_out;

  float* ws_kv    = (float*)d_ws;                       // 64MB
  float* ws_decay = ws_kv + (size_t)NBH * NCH * 4096;   // 4096 floats

  k1_kvdecay<<<dim3(NBH * NCH), dim3(256), 0, stream>>>(
      k, v, w_decay, b_decay, w_write, b_write, ws_kv, ws_decay);
  k2_scan<<<dim3(256), dim3(256), 0, stream>>>(ws_kv, ws_decay);
  k3_out<<<dim3(NBH * NCH), dim3(256), 0, stream>>>(
      q, k, v, w_write, b_write, out_scale, ws_kv, out);
}

// Round 6
// 283.539 us; speedup vs baseline: 2.0812x; 1.0181x over previous
//
#include <hip/hip_runtime.h>
#include <math.h>

// DeltaCorrection via split-bf16 MFMA (3-term Ootomo: hi*hi + hi*lo + lo*hi).
// K1: per-chunk kv (d x d) + chunk decay      (4096 blocks, MFMA, 4 blocks/CU)
// K2: scan; stores S_{c-1} PRE-SPLIT into bf16 hi/lo cells, in-place
// K3: scoresT (causal tiles only) -> masked ss -> out = q*S^T + ss*v
//     (4096 blocks, 3 blocks/CU, S-cells loaded at kernel start, 3 barriers)

#define NCH 64
#define NBH 64

typedef __attribute__((ext_vector_type(8))) short bf16x8;
typedef __attribute__((ext_vector_type(4))) float f32x4;
typedef unsigned short ushort_t;

#define MFMA(a, b, c) __builtin_amdgcn_mfma_f32_16x16x32_bf16(a, b, c, 0, 0, 0)
#define GETC(v, u) ((u) == 0 ? (v).x : ((u) == 1 ? (v).y : ((u) == 2 ? (v).z : (v).w)))

__device__ __forceinline__ float sigf(float x) { return 1.0f / (1.0f + expf(-x)); }

// byte offset into a [64][64] bf16 LDS array, XOR-swizzled so that b128 reads
// across lane-varying rows at fixed 16B col-slot spread over 8 bank-slots.
__device__ __forceinline__ int swb(int row, int col) {
  return ((row << 7) + (col << 1)) ^ ((row & 7) << 4);
}

// split fp32 -> truncated bf16 hi + bf16(residual) lo.  |x - hi - lo| <= 2^-16 |x|
__device__ __forceinline__ void split1(float x, ushort_t& h, ushort_t& l) {
  unsigned xb = __float_as_uint(x);
  h = (ushort_t)(xb >> 16);
  float hf = __uint_as_float(xb & 0xFFFF0000u);
  float lf = x - hf;
  l = (ushort_t)(__float_as_uint(lf) >> 16);
}

// store float4 as hi/lo bf16, b64-packed, at (row, col..col+3); col % 4 == 0
__device__ __forceinline__ void st_split4(char* bh, char* bl, int row, int col, float4 v) {
  ushort_t h0, h1, h2, h3, l0, l1, l2, l3;
  split1(v.x, h0, l0); split1(v.y, h1, l1); split1(v.z, h2, l2); split1(v.w, h3, l3);
  uint2 hp, lp;
  hp.x = (unsigned)h0 | ((unsigned)h1 << 16); hp.y = (unsigned)h2 | ((unsigned)h3 << 16);
  lp.x = (unsigned)l0 | ((unsigned)l1 << 16); lp.y = (unsigned)l2 | ((unsigned)l3 << 16);
  int o = swb(row, col);
  *(uint2*)(bh + o) = hp;
  *(uint2*)(bl + o) = lp;
}

// A/B fragment for mfma_f32_16x16x32_bf16: lane holds row mrow+(lane&15),
// k = kk + (lane>>4)*8 .. +7 (contiguous in the stored tile)
__device__ __forceinline__ bf16x8 ldfrag(const char* base, int mrow, int kk, int lane) {
  int r = mrow + (lane & 15);
  int c = kk + ((lane >> 4) << 3);
  return *(const bf16x8*)(base + swb(r, c));
}

// ---------------------------------------------------------------------------
// K1: kv[i][j] = sum_t v[t][i] * (beta_t * khat[t][j]);  decay[bh][c]
// ---------------------------------------------------------------------------
__global__ __launch_bounds__(256, 4) void k1_kvdecay(
    const float* __restrict__ kg, const float* __restrict__ vg,
    const float* __restrict__ w_decay, const float* __restrict__ b_decay,
    const float* __restrict__ w_write, const float* __restrict__ b_write,
    float* __restrict__ ws_kv, float* __restrict__ ws_decay) {
  __shared__ uint4 smraw[2064];  // 33 KB -> 4 blocks/CU
  char* sm = (char*)smraw;
  char* KT_H = sm;             // kf^T [j][t] hi   (j = feature, t = time)
  char* KT_L = sm + 8192;
  char* VT_H = sm + 16384;     // v^T  [i][t]
  char* VT_L = sm + 24576;
  float* abuf = (float*)(sm + 32768);

  const int tid = threadIdx.x;
  const int lane = tid & 63, wv = tid >> 6;
  const int bh = blockIdx.x >> 6, cid = blockIdx.x & 63;
  const size_t gbase = (size_t)(bh * 4096 + cid * 64) * 64;

  // ---- load + gates + scatter-transpose staging ----
  {
    const int t = tid >> 2, g = tid & 3;
    const float* kp = kg + gbase + t * 64 + g * 16;
    const float* vp = vg + gbase + t * 64 + g * 16;
    float4 kr[4], vr[4];
#pragma unroll
    for (int u = 0; u < 4; ++u) { kr[u] = *(const float4*)(kp + 4 * u); vr[u] = *(const float4*)(vp + 4 * u); }
    float n2 = 0.f, dw = 0.f, da = 0.f;
#pragma unroll
    for (int u = 0; u < 4; ++u) {
      const float* wwp = w_write + g * 16 + 4 * u;
      const float* wdp = w_decay + g * 16 + 4 * u;
      float4 k4 = kr[u];
      n2 = fmaf(k4.x, k4.x, fmaf(k4.y, k4.y, fmaf(k4.z, k4.z, fmaf(k4.w, k4.w, n2))));
      dw = fmaf(k4.x, wwp[0], fmaf(k4.y, wwp[1], fmaf(k4.z, wwp[2], fmaf(k4.w, wwp[3], dw))));
      da = fmaf(k4.x, wdp[0], fmaf(k4.y, wdp[1], fmaf(k4.z, wdp[2], fmaf(k4.w, wdp[3], da))));
    }
    n2 += __shfl_xor(n2, 1, 64); n2 += __shfl_xor(n2, 2, 64);
    dw += __shfl_xor(dw, 1, 64); dw += __shfl_xor(dw, 2, 64);
    da += __shfl_xor(da, 1, 64); da += __shfl_xor(da, 2, 64);
    float beta  = sigf(dw + b_write[0]);
    float alpha = sigf(da + b_decay[0]);
    float fold  = beta / fmaxf(sqrtf(n2), 1e-12f);
    if (g == 0) abuf[t] = alpha;
#pragma unroll
    for (int u = 0; u < 4; ++u) {
      float kf[4] = {kr[u].x * fold, kr[u].y * fold, kr[u].z * fold, kr[u].w * fold};
      float vf[4] = {vr[u].x, vr[u].y, vr[u].z, vr[u].w};
#pragma unroll
      for (int e = 0; e < 4; ++e) {
        int row = g * 16 + 4 * u + e;
        ushort_t h, l;
        int o = swb(row, t);
        split1(kf[e], h, l);
        *(ushort_t*)(KT_H + o) = h; *(ushort_t*)(KT_L + o) = l;
        split1(vf[e], h, l);
        *(ushort_t*)(VT_H + o) = h; *(ushort_t*)(VT_L + o) = l;
      }
    }
  }
  __syncthreads();

  // ---- chunk decay (wave 0) ----
  if (tid < 64) {
    float a = abuf[tid];
    for (int off = 32; off; off >>= 1) a += __shfl_down(a, off, 64);
    if (tid == 0) {
      float m = a * (1.0f / 64.0f);
      float p = m * m; p = p * p; p = p * p; p = p * p; p = p * p; p = p * p;  // m^64
      ws_decay[bh * NCH + cid] = p;
    }
  }

  // ---- kv = mfma(A=v^T [i][t], B-src=kf^T [j][t]) -> D[i][j]; direct stores ----
  f32x4 z = {0.f, 0.f, 0.f, 0.f};
  f32x4 acc[4] = {z, z, z, z};
#pragma unroll
  for (int kk = 0; kk < 64; kk += 32) {
    bf16x8 ah = ldfrag(VT_H, wv * 16, kk, lane);
    bf16x8 al = ldfrag(VT_L, wv * 16, kk, lane);
#pragma unroll
    for (int jb = 0; jb < 4; ++jb) {
      bf16x8 bh_ = ldfrag(KT_H, jb * 16, kk, lane);
      bf16x8 bl_ = ldfrag(KT_L, jb * 16, kk, lane);
      acc[jb] = MFMA(ah, bh_, acc[jb]);
      acc[jb] = MFMA(ah, bl_, acc[jb]);
      acc[jb] = MFMA(al, bh_, acc[jb]);
    }
  }
  float* kvout = ws_kv + (size_t)(bh * NCH + cid) * 4096;
  {
    int i0 = wv * 16 + ((lane >> 4) << 2);
#pragma unroll
    for (int jb = 0; jb < 4; ++jb) {
      int j = jb * 16 + (lane & 15);
#pragma unroll
      for (int r = 0; r < 4; ++r) kvout[(i0 + r) * 64 + j] = acc[jb][r];
    }
  }
}

// ---------------------------------------------------------------------------
// K2: in-place scan. Reads fp32 kv cells; writes S_{c-1} PRE-SPLIT as
// {hi01,hi23,lo01,lo23} uint4 at the SAME byte address (thread-private RMW).
// After: slot c holds split(S_{c-1}) (slot 0 = zeros).
// ---------------------------------------------------------------------------
__global__ __launch_bounds__(256) void k2_scan(float* __restrict__ ws_kv,
                                               const float* __restrict__ ws_decay) {
  const int bh = blockIdx.x >> 2;
  const int pos = (blockIdx.x & 3) * 256 + threadIdx.x;  // 16B cell index 0..1023
  uint4* base = (uint4*)ws_kv + (size_t)bh * 65536 + pos;
  const float* dec = ws_decay + bh * NCH;
  float4 S = make_float4(0.f, 0.f, 0.f, 0.f);
#pragma unroll
  for (int gq = 0; gq < 8; ++gq) {
    uint4 raw[8];
#pragma unroll
    for (int j = 0; j < 8; ++j) raw[j] = base[(size_t)(gq * 8 + j) * 1024];
#pragma unroll
    for (int j = 0; j < 8; ++j) {
      int c = gq * 8 + j;
      float dcy = dec[c];
      float4 kv = *(float4*)&raw[j];
      ushort_t h0, h1, h2, h3, l0, l1, l2, l3;
      split1(S.x, h0, l0); split1(S.y, h1, l1); split1(S.z, h2, l2); split1(S.w, h3, l3);
      uint4 w;
      w.x = (unsigned)h0 | ((unsigned)h1 << 16); w.y = (unsigned)h2 | ((unsigned)h3 << 16);
      w.z = (unsigned)l0 | ((unsigned)l1 << 16); w.w = (unsigned)l2 | ((unsigned)l3 << 16);
      base[(size_t)c * 1024] = w;
      S.x = fmaf(dcy, S.x, kv.x);
      S.y = fmaf(dcy, S.y, kv.y);
      S.z = fmaf(dcy, S.z, kv.z);
      S.w = fmaf(dcy, S.w, kv.w);
    }
  }
}

// ---------------------------------------------------------------------------
// K3: ssT[j][t] = kf[j].q[t] (causal tiles only) ; out[t][i] = q.S^T + ss.v
// LDS 48KB: QS, KS (PS aliases KS after phase A), VT. S-cells from global,
// loaded at kernel start, repacked to bf16 frags with pure reg movs.
// ---------------------------------------------------------------------------
__global__ __launch_bounds__(256, 3) void k3_out(
    const float* __restrict__ qg, const float* __restrict__ kg,
    const float* __restrict__ vg,
    const float* __restrict__ w_write, const float* __restrict__ b_write,
    const float* __restrict__ out_scale,
    const float* __restrict__ ws_kv, float* __restrict__ outg) {
  __shared__ uint4 smraw[3072];  // 48 KB -> 3 blocks/CU
  char* sm = (char*)smraw;
  char* QS_H = sm;             char* QS_L = sm + 8192;   // q   [t][d]
  char* KS_H = sm + 16384;     char* KS_L = sm + 24576;  // kf  [j][d]; ss [t][tau] after p1a
  char* VT_H = sm + 32768;     char* VT_L = sm + 40960;  // v^T [i][t]
  char* PS_H = KS_H;           char* PS_L = KS_L;

  const int tid = threadIdx.x;
  const int lane = tid & 63, wv = tid >> 6;
  const int bh = blockIdx.x >> 6, cid = blockIdx.x & 63;
  const size_t gbase = (size_t)(bh * 4096 + cid * 64) * 64;

  // ---- S split-cell loads (issued first; consumed in phase B) ----
  uint4 scell[16];
  {
    const uint4* Sg4 = (const uint4*)(ws_kv) + (size_t)(bh * NCH + cid) * 1024;
    const int l15 = lane & 15, cc0 = (lane >> 4) << 1;
#pragma unroll
    for (int ib = 0; ib < 4; ++ib) {
#pragma unroll
      for (int k2 = 0; k2 < 2; ++k2) {
        const uint4* p = Sg4 + (ib * 16 + l15) * 16 + k2 * 8 + cc0;
        scell[ib * 4 + k2 * 2 + 0] = p[0];
        scell[ib * 4 + k2 * 2 + 1] = p[1];
      }
    }
  }

  // ---- stage q ----
#pragma unroll
  for (int rr = 0; rr < 4; ++rr) {
    int f = tid + 256 * rr;
    int row = f >> 4, c4 = (f & 15) * 4;
    float4 qq = *(const float4*)(qg + gbase + row * 64 + c4);
    st_split4(QS_H, QS_L, row, c4, qq);
  }
  // ---- stage v^T via 4x4 register transpose (b64 LDS writes) ----
  {
    const int rq = tid & 15, cq = tid >> 4;
    float4 vv[4];
#pragma unroll
    for (int e = 0; e < 4; ++e)
      vv[e] = *(const float4*)(vg + gbase + (4 * rq + e) * 64 + 4 * cq);
#pragma unroll
    for (int m = 0; m < 4; ++m) {
      float4 tv = make_float4(GETC(vv[0], m), GETC(vv[1], m), GETC(vv[2], m), GETC(vv[3], m));
      st_split4(VT_H, VT_L, 4 * cq + m, 4 * rq, tv);
    }
  }
  // ---- stage kf (fold beta/norm in registers) ----
  {
    const int t = tid >> 2, g = tid & 3;
    const float* kp = kg + gbase + t * 64 + g * 16;
    float4 kr[4];
#pragma unroll
    for (int u = 0; u < 4; ++u) kr[u] = *(const float4*)(kp + 4 * u);
    float n2 = 0.f, dw = 0.f;
#pragma unroll
    for (int u = 0; u < 4; ++u) {
      const float* wwp = w_write + g * 16 + 4 * u;
      float4 k4 = kr[u];
      n2 = fmaf(k4.x, k4.x, fmaf(k4.y, k4.y, fmaf(k4.z, k4.z, fmaf(k4.w, k4.w, n2))));
      dw = fmaf(k4.x, wwp[0], fmaf(k4.y, wwp[1], fmaf(k4.z, wwp[2], fmaf(k4.w, wwp[3], dw))));
    }
    n2 += __shfl_xor(n2, 1, 64); n2 += __shfl_xor(n2, 2, 64);
    dw += __shfl_xor(dw, 1, 64); dw += __shfl_xor(dw, 2, 64);
    float beta = sigf(dw + b_write[0]);
    float fold = beta / fmaxf(sqrtf(n2), 1e-12f);
#pragma unroll
    for (int u = 0; u < 4; ++u) {
      float4 kf4 = make_float4(kr[u].x * fold, kr[u].y * fold, kr[u].z * fold, kr[u].w * fold);
      st_split4(KS_H, KS_L, t, g * 16 + 4 * u, kf4);
    }
  }
  __syncthreads();

  // ---- phase A: ssT[j][t] tiles with jb<=tb only (causal skip),
  //      rebalanced 3/3/2/2 tiles per wave; all coords compile-time ----
  const f32x4 z = {0.f, 0.f, 0.f, 0.f};
  f32x4 sc0 = z, sc1 = z, sc2 = z;
  auto tileA = [&](int jb, int tb, f32x4& acc) {
#pragma unroll
    for (int kk = 0; kk < 64; kk += 32) {
      bf16x8 ah = ldfrag(KS_H, jb * 16, kk, lane);
      bf16x8 al = ldfrag(KS_L, jb * 16, kk, lane);
      bf16x8 bh_ = ldfrag(QS_H, tb * 16, kk, lane);
      bf16x8 bl_ = ldfrag(QS_L, tb * 16, kk, lane);
      acc = MFMA(ah, bh_, acc);
      acc = MFMA(ah, bl_, acc);
      acc = MFMA(al, bh_, acc);
    }
  };
  if (wv == 0)      { tileA(0, 0, sc0); tileA(1, 1, sc1); tileA(2, 2, sc2); }
  else if (wv == 1) { tileA(3, 3, sc0); tileA(0, 1, sc1); tileA(1, 2, sc2); }
  else if (wv == 2) { tileA(2, 3, sc0); tileA(0, 2, sc1); }
  else              { tileA(1, 3, sc0); tileA(0, 3, sc1); }
  __syncthreads();  // all phase-A reads of KS/QS done -> PS may overwrite KS

  // ---- write scores to PS [t][j]: diag masked, sub-diag full, super zero ----
  auto psMask = [&](int jb, int tb, f32x4 a) {
    int tcol = tb * 16 + (lane & 15);
    int j0 = jb * 16 + ((lane >> 4) << 2);
    float x0 = (j0 + 0 <= tcol) ? a[0] : 0.f;
    float x1 = (j0 + 1 <= tcol) ? a[1] : 0.f;
    float x2 = (j0 + 2 <= tcol) ? a[2] : 0.f;
    float x3 = (j0 + 3 <= tcol) ? a[3] : 0.f;
    st_split4(PS_H, PS_L, tcol, j0, make_float4(x0, x1, x2, x3));
  };
  auto psFull = [&](int jb, int tb, f32x4 a) {
    st_split4(PS_H, PS_L, tb * 16 + (lane & 15), jb * 16 + ((lane >> 4) << 2),
              make_float4(a[0], a[1], a[2], a[3]));
  };
  auto psZero = [&](int jb, int tb) {
    st_split4(PS_H, PS_L, tb * 16 + (lane & 15), jb * 16 + ((lane >> 4) << 2),
              make_float4(0.f, 0.f, 0.f, 0.f));
  };
  if (wv == 0)      { psMask(0, 0, sc0); psMask(1, 1, sc1); psMask(2, 2, sc2); psZero(1, 0); psZero(2, 1); }
  else if (wv == 1) { psMask(3, 3, sc0); psFull(0, 1, sc1); psFull(1, 2, sc2); psZero(2, 0); psZero(3, 2); }
  else if (wv == 2) { psFull(2, 3, sc0); psFull(0, 2, sc1); psZero(3, 0); }
  else              { psFull(1, 3, sc0); psFull(0, 3, sc1); psZero(3, 1); }
  __syncthreads();

  // ---- phase B: out[t][i] = sum_j q[t][j] S[i][j] + sum_j ss[t][j] vT[i][j] ----
  f32x4 acco[4] = {z, z, z, z};
#pragma unroll
  for (int k2 = 0; k2 < 2; ++k2) {
    const int kk = k2 * 32;
    bf16x8 qh = ldfrag(QS_H, wv * 16, kk, lane);
    bf16x8 ql = ldfrag(QS_L, wv * 16, kk, lane);
    bf16x8 ph = ldfrag(PS_H, wv * 16, kk, lane);
    bf16x8 pl = ldfrag(PS_L, wv * 16, kk, lane);
#pragma unroll
    for (int ib = 0; ib < 4; ++ib) {
      uint4 cA = scell[ib * 4 + k2 * 2 + 0];
      uint4 cB = scell[ib * 4 + k2 * 2 + 1];
      uint4 th = make_uint4(cA.x, cA.y, cB.x, cB.y);
      uint4 tl = make_uint4(cA.z, cA.w, cB.z, cB.w);
      bf16x8 sh = *(bf16x8*)&th;
      bf16x8 sl = *(bf16x8*)&tl;
      acco[ib] = MFMA(qh, sh, acco[ib]);   // inter
      acco[ib] = MFMA(qh, sl, acco[ib]);
      acco[ib] = MFMA(ql, sh, acco[ib]);
      bf16x8 vh = ldfrag(VT_H, ib * 16, kk, lane);
      bf16x8 vl = ldfrag(VT_L, ib * 16, kk, lane);
      acco[ib] = MFMA(ph, vh, acco[ib]);   // intra
      acco[ib] = MFMA(ph, vl, acco[ib]);
      acco[ib] = MFMA(pl, vh, acco[ib]);
    }
  }

  // ---- direct C-stores (64B segments per 16-lane group) ----
  const float osc = out_scale[0];
  {
    int t0 = wv * 16 + ((lane >> 4) << 2);
    int l15 = lane & 15;
#pragma unroll
    for (int ib = 0; ib < 4; ++ib) {
#pragma unroll
      for (int r = 0; r < 4; ++r)
        outg[gbase + (t0 + r) * 64 + ib * 16 + l15] = acco[ib][r] * osc;
    }
  }
}

// ---------------------------------------------------------------------------
extern "C" void kernel_launch(void* const* d_in, const int* in_sizes, int n_in,
                              void* d_out, int out_size, void* d_ws, size_t ws_size,
                              hipStream_t stream) {
  const float* q         = (const float*)d_in[0];
  const float* k         = (const float*)d_in[1];
  const float* v         = (const float*)d_in[2];
  const float* w_decay   = (const float*)d_in[3];
  const float* b_decay   = (const float*)d_in[4];
  const float* w_write   = (const float*)d_in[5];
  const float* b_write   = (const float*)d_in[6];
  const float* out_scale = (const float*)d_in[7];
  float* out = (float*)d_out;

  float* ws_kv    = (float*)d_ws;                       // 64MB
  float* ws_decay = ws_kv + (size_t)NBH * NCH * 4096;   // 4096 floats

  k1_kvdecay<<<dim3(NBH * NCH), dim3(256), 0, stream>>>(
      k, v, w_decay, b_decay, w_write, b_write, ws_kv, ws_decay);
  k2_scan<<<dim3(256), dim3(256), 0, stream>>>(ws_kv, ws_decay);
  k3_out<<<dim3(NBH * NCH), dim3(256), 0, stream>>>(
      q, k, v, w_write, b_write, out_scale, ws_kv, out);
}